// Round 2
// 1114.373 us; speedup vs baseline: 1.0397x; 1.0397x over previous
//
#include <hip/hip_runtime.h>

#define B_SZ 32
#define NSEQ 4096
#define DM   1024
#define NH   16
#define NS   4    // n-splits for ctx pass (keeps ctxp at the proven 8 MiB)

typedef __attribute__((ext_vector_type(8))) short bf16x8;
typedef __attribute__((ext_vector_type(4))) short s16x4;
typedef __attribute__((ext_vector_type(4))) float f32x4;

// fp32 -> bf16 bits, round-to-nearest-even
__device__ __forceinline__ short f2bf(float f) {
  unsigned int x = __float_as_uint(f);
  unsigned int r = (x + 0x7fffu + ((x >> 16) & 1u)) >> 16;
  return (short)r;
}

// Pass 0: qw[b,h,D] = (1/8) * sum_d (query[b,:]·wq[:,h*64+d]) * wk[D, h*64+d]
// grid: 512 blocks (b*16+h), 256 threads
__global__ __launch_bounds__(256) void qw_kernel(
    const float* __restrict__ query, const float* __restrict__ wq,
    const float* __restrict__ wk, short* __restrict__ qw16) {
  int b = blockIdx.x >> 4, h = blockIdx.x & 15;
  int t = threadIdx.x;
  __shared__ float qs[DM];
  __shared__ float red[256];
  __shared__ float qh[64];
  ((f32x4*)qs)[t] = ((const f32x4*)(query + (size_t)b * DM))[t];
  __syncthreads();
  int q = t >> 6, d = t & 63;
  {
    const float* wqc = wq + h * 64 + d;
    float acc = 0.f;
    #pragma unroll 8
    for (int D = q * 256; D < q * 256 + 256; ++D)
      acc += qs[D] * wqc[(size_t)D * DM];
    red[t] = acc;
  }
  __syncthreads();
  if (t < 64)
    qh[t] = (red[t] + red[t + 64] + red[t + 128] + red[t + 192]) * 0.125f;
  __syncthreads();
  for (int k = 0; k < 4; ++k) {
    int D = t + 256 * k;
    const f32x4* wk4 = (const f32x4*)(wk + (size_t)D * DM + h * 64);
    float a = 0.f;
    #pragma unroll
    for (int j = 0; j < 16; ++j) {
      f32x4 w = wk4[j];
      a += qh[j * 4 + 0] * w[0] + qh[j * 4 + 1] * w[1] +
           qh[j * 4 + 2] * w[2] + qh[j * 4 + 3] * w[3];
    }
    qw16[((size_t)b * NH + h) * DM + D] = f2bf(a);
  }
}

// Pass A: scores[b,h,n] = key[b,n,:] · qw[b,h,:]
// grid: 2048 blocks (b*64 + ngroup of 64 rows), 256 threads = 4 waves.
// Key staged via contiguous 1KB-per-wave loads into padded LDS (bf16);
// MFMA A-fragments via ds_read_b128. Pad +8 cols: row stride 528B ->
// lane lm lands at bank lm*4 mod 32 -> 2-way (free) instead of 16-way.
__global__ __launch_bounds__(256) void scores_kernel(
    const float* __restrict__ key, const short* __restrict__ qw16,
    float* __restrict__ scores) {
  int blk = blockIdx.x;
  int b = blk >> 6, ng = blk & 63;
  int n0 = ng * 64;
  int t = threadIdx.x;
  int wave = t >> 6, lane = t & 63, quad = lane >> 4, lm = lane & 15;
  __shared__ short kt[64][264];   // 264 = 256 + 8 pad (row stride 528B, 16B-aligned)
  const float* kbase = key + ((size_t)b * NSEQ + n0) * DM;
  const short* bb = qw16 + ((size_t)b * NH + lm) * DM + quad * 8;
  f32x4 acc = {0.f, 0.f, 0.f, 0.f};
  for (int kch = 0; kch < 4; ++kch) {
    // stage: wave w reads row i*4+w, 1KB contiguous per wave-instruction
    #pragma unroll
    for (int i = 0; i < 16; ++i) {
      int r = i * 4 + wave;
      f32x4 v = *(const f32x4*)(kbase + (size_t)r * DM + kch * 256 + lane * 4);
      s16x4 p;
      p[0] = f2bf(v[0]); p[1] = f2bf(v[1]);
      p[2] = f2bf(v[2]); p[3] = f2bf(v[3]);
      *(s16x4*)&kt[r][lane * 4] = p;
    }
    __syncthreads();
    #pragma unroll
    for (int kc = 0; kc < 8; ++kc) {
      bf16x8 afrag = *(const bf16x8*)&kt[wave * 16 + lm][kc * 32 + quad * 8];
      bf16x8 bfrag = *(const bf16x8*)(bb + kch * 256 + kc * 32);
      acc = __builtin_amdgcn_mfma_f32_16x16x32_bf16(afrag, bfrag, acc, 0, 0, 0);
    }
    __syncthreads();
  }
  // D layout: row(n-off) = quad*4 + r, col(h) = lm
  size_t sidx = ((size_t)b * NH + lm) * NSEQ + n0 + wave * 16 + quad * 4;
  *(f32x4*)(scores + sidx) = acc;
}

// Pass B: row softmax over N=4096, output bf16 P[b,h,n]
__global__ __launch_bounds__(256) void softmax_kernel(
    const float* __restrict__ scores, short* __restrict__ P) {
  int bh = blockIdx.x;
  int t = threadIdx.x;
  int lane = t & 63, wave = t >> 6;
  const f32x4* row = (const f32x4*)(scores + (size_t)bh * NSEQ);
  f32x4 v[4];
  float m = -1e30f;
  #pragma unroll
  for (int i = 0; i < 4; ++i) {
    v[i] = row[t + 256 * i];
    m = fmaxf(m, fmaxf(fmaxf(v[i][0], v[i][1]), fmaxf(v[i][2], v[i][3])));
  }
  #pragma unroll
  for (int off = 32; off > 0; off >>= 1) m = fmaxf(m, __shfl_xor(m, off));
  __shared__ float sm[4], ss[4];
  if (lane == 0) sm[wave] = m;
  __syncthreads();
  m = fmaxf(fmaxf(sm[0], sm[1]), fmaxf(sm[2], sm[3]));
  float s = 0.f;
  #pragma unroll
  for (int i = 0; i < 4; ++i)
    #pragma unroll
    for (int j = 0; j < 4; ++j) { v[i][j] = __expf(v[i][j] - m); s += v[i][j]; }
  #pragma unroll
  for (int off = 32; off > 0; off >>= 1) s += __shfl_xor(s, off);
  if (lane == 0) ss[wave] = s;
  __syncthreads();
  float inv = 1.f / (ss[0] + ss[1] + ss[2] + ss[3]);
  short* Pr = P + (size_t)bh * NSEQ;
  #pragma unroll
  for (int i = 0; i < 4; ++i) {
    short4 p;
    p.x = f2bf(v[i][0] * inv); p.y = f2bf(v[i][1] * inv);
    p.z = f2bf(v[i][2] * inv); p.w = f2bf(v[i][3] * inv);
    *(short4*)(Pr + (size_t)(t + 256 * i) * 4) = p;
  }
}

// Pass C: ctxp[ns][b][h][D] = sum_{n in split of 1024} P[b,h,n] * value[b,n,D]
// grid: 512 blocks (b*16 + Dg*4 + ns), 256 threads = 4 waves.
// Each block owns 256 D-columns -> V staging is a full 1KB row per wave
// per instruction (fully contiguous). Pad +4 cols: quad-rows (stride 8
// rows = 1040 words) land 16 banks apart -> 2-way (free) on the
// per-element B-fragment reads.
__global__ __launch_bounds__(256) void ctx_kernel(
    const float* __restrict__ value, const short* __restrict__ P,
    float* __restrict__ ctxp) {
  int blk = blockIdx.x;
  int b  = blk >> 4;
  int Dg = (blk >> 2) & 3;
  int ns = blk & 3;
  int t = threadIdx.x;
  int wave = t >> 6, lane = t & 63, quad = lane >> 4, lm = lane & 15;
  __shared__ short vt[32][260];   // 260 = 256 + 4 pad (row stride 520B, 8B-aligned)
  const float* vbase = value + ((size_t)b * NSEQ + ns * 1024) * DM + Dg * 256;
  const short* pbase = P + ((size_t)b * NH + lm) * NSEQ + ns * 1024 + quad * 8;
  f32x4 acc[4];
  #pragma unroll
  for (int i = 0; i < 4; ++i) acc[i] = (f32x4){0.f, 0.f, 0.f, 0.f};
  for (int nc = 0; nc < 32; ++nc) {
    // stage 32 n-rows x 256 cols: wave w covers rows w, w+4, ... (1KB contig each)
    const float* src = vbase + (size_t)(nc * 32 + wave) * DM + lane * 4;
    #pragma unroll
    for (int i = 0; i < 8; ++i) {
      f32x4 v = *(const f32x4*)(src + (size_t)(i * 4) * DM);
      s16x4 p;
      p[0] = f2bf(v[0]); p[1] = f2bf(v[1]);
      p[2] = f2bf(v[2]); p[3] = f2bf(v[3]);
      *(s16x4*)&vt[wave + i * 4][lane * 4] = p;
    }
    __syncthreads();
    // A: P rows (m = h = lm, k = n = nc*32 + quad*8 + j)
    bf16x8 pfrag = *(const bf16x8*)(pbase + nc * 32);
    #pragma unroll
    for (int dt = 0; dt < 4; ++dt) {
      int cb = wave * 64 + dt * 16 + lm;           // D column within group
      bf16x8 bfrag;
      #pragma unroll
      for (int j = 0; j < 8; ++j)
        bfrag[j] = vt[quad * 8 + j][cb];           // k = quad*8 + j
      acc[dt] = __builtin_amdgcn_mfma_f32_16x16x32_bf16(pfrag, bfrag, acc[dt], 0, 0, 0);
    }
    __syncthreads();
  }
  // D layout: row(h) = quad*4 + r, col(D) = lm
  #pragma unroll
  for (int dt = 0; dt < 4; ++dt) {
    int Dc = Dg * 256 + wave * 64 + dt * 16 + lm;
    #pragma unroll
    for (int r = 0; r < 4; ++r) {
      int h = quad * 4 + r;
      ctxp[(((size_t)ns * B_SZ + b) * NH + h) * DM + Dc] = acc[dt][r];
    }
  }
}

// Pass D: out[b, h*64+d] = sum_D (sum_ns ctxp[ns,b,h,D]) * wv[D, h*64+d]
__global__ __launch_bounds__(256) void out_kernel(
    const float* __restrict__ ctxp, const float* __restrict__ wv,
    float* __restrict__ out) {
  int b = blockIdx.x >> 4, h = blockIdx.x & 15;
  int t = threadIdx.x;
  __shared__ float ctx[DM];
  for (int i = t; i < DM; i += 256) {
    float s = 0.f;
    #pragma unroll
    for (int ns = 0; ns < NS; ++ns)
      s += ctxp[(((size_t)ns * B_SZ + b) * NH + h) * DM + i];
    ctx[i] = s;
  }
  __syncthreads();
  int d = t & 63, q = t >> 6;
  float acc = 0.f;
  #pragma unroll 4
  for (int D = q * 256; D < (q + 1) * 256; ++D)
    acc += ctx[D] * wv[(size_t)D * DM + h * 64 + d];
  __shared__ float red[256];
  red[t] = acc;
  __syncthreads();
  if (t < 64)
    out[(size_t)b * DM + h * 64 + t] =
        red[t] + red[t + 64] + red[t + 128] + red[t + 192];
}

extern "C" void kernel_launch(void* const* d_in, const int* in_sizes, int n_in,
                              void* d_out, int out_size, void* d_ws, size_t ws_size,
                              hipStream_t stream) {
  const float* query = (const float*)d_in[0];
  const float* key   = (const float*)d_in[1];
  const float* value = (const float*)d_in[2];
  const float* wq    = (const float*)d_in[3];
  const float* wk    = (const float*)d_in[4];
  const float* wv    = (const float*)d_in[5];
  float* out = (float*)d_out;
  char* ws = (char*)d_ws;

  // identical footprint to the proven round-0 layout (21 MiB total)
  short* qw16   = (short*)(ws);                    // 1 MiB: [32][16][1024] bf16
  float* scores = (float*)(ws + (1u << 20));       // 8 MiB: [32][16][4096] f32
  short* P      = (short*)(ws + (9u << 20));       // 4 MiB: [32][16][4096] bf16
  float* ctxp   = (float*)(ws + (13u << 20));      // 8 MiB: [4][32][16][1024] f32

  qw_kernel     <<<B_SZ * NH, 256, 0, stream>>>(query, wq, wk, qw16);
  scores_kernel <<<B_SZ * 64, 256, 0, stream>>>(key, qw16, scores);
  softmax_kernel<<<B_SZ * NH, 256, 0, stream>>>(scores, P);
  ctx_kernel    <<<B_SZ * 16, 256, 0, stream>>>(value, P, ctxp);
  out_kernel    <<<B_SZ * NH, 256, 0, stream>>>(ctxp, wv, out);
}